// Round 7
// baseline (249.820 us; speedup 1.0000x reference)
//
#include <hip/hip_runtime.h>
#include <hip/hip_bf16.h>
#include <string.h>

#define E_CNT 500000
#define N_CNT 100000
#define HID   256
#define NTILE 31250   // E/16

typedef short short8 __attribute__((ext_vector_type(8)));
typedef float f32x4 __attribute__((ext_vector_type(4)));

__device__ __forceinline__ unsigned short f2bf(float f){
  union { float f; unsigned int i; } v; v.f = f;
  unsigned int u = v.i;
  u = u + 0x7FFFu + ((u >> 16) & 1u);
  return (unsigned short)(u >> 16);
}

__device__ __forceinline__ unsigned int pk_bf16(float a, float b){
  __hip_bfloat162 p = __float22bfloat162_rn(make_float2(a, b));
  unsigned int u; memcpy(&u, &p, 4); return u;
}

// Stage W1-augmented A-fragments in LDS (coalesced init), then each lane
// hoists its 16 fragments into registers ONCE (outside the memory-clobbered
// K-loop).  Row ch: k0..7=W1[k][ch], k8..15=W1 again, k16=2*b1, k17..23=0.
__device__ __forceinline__ void init_w1_lds(unsigned short* w1l,
                                            const float* W1, const float* b1,
                                            int tid){
  int ch = tid;
  #pragma unroll
  for (int j = 0; j < 8; ++j){
    unsigned short w = f2bf(W1[j * HID + ch]);
    w1l[ch * 24 + j]     = w;
    w1l[ch * 24 + 8 + j] = w;
  }
  w1l[ch * 24 + 16] = f2bf(2.0f * b1[ch]);
  #pragma unroll
  for (int j = 17; j < 24; ++j) w1l[ch * 24 + j] = 0;
  if (tid < 32) w1l[256 * 24 + tid] = 0;   // tail pad for q=3 of ch=255
}

// ---------------- K1: batch stats of h' = relu((nf[s]+nf[t])@W1 + 2 b1) ------
__global__ __launch_bounds__(256, 3) void k1_stats(
    const int* __restrict__ eidx, const float* __restrict__ nf,
    const float* __restrict__ W1, const float* __restrict__ b1,
    float* __restrict__ part, float* __restrict__ bd2)
{
  __shared__ unsigned short w1l[256 * 24 + 32];
  __shared__ unsigned short ctx[4][16 * 40];
  __shared__ float sred[2][4][256];

  const int tid = threadIdx.x, lane = tid & 63, wid = tid >> 6;
  const int gw = blockIdx.x * 4 + wid, nw = gridDim.x * 4;
  const int m = lane & 15, q = lane >> 4;
  const int r = lane >> 2, side = (lane >> 1) & 1, half = lane & 1;

  if (blockIdx.x == 0 && tid < 16) bd2[tid] = 0.f;   // kC atomicAdds later

  init_w1_lds(w1l, W1, b1, tid);

  unsigned short* myctx = ctx[wid];
  for (int i = lane; i < 16 * 40; i += 64) myctx[i] = 0;
  if (lane < 16) myctx[lane * 40 + 16] = 0x3F80;   // bf16 1.0 at k=16
  __syncthreads();

  short8 w1fr[16];                 // hoisted: read LDS once, keep in regs
  #pragma unroll
  for (int nt = 0; nt < 16; ++nt)
    w1fr[nt] = *(const short8*)&w1l[(nt * 16 + m) * 24 + q * 8];

  const f32x4 z4 = {0.f, 0.f, 0.f, 0.f};
  f32x4 sacc[16], qacc[16];
  #pragma unroll
  for (int nt = 0; nt < 16; ++nt){ sacc[nt] = z4; qacc[nt] = z4; }

  int t = gw;
  float4 nfc = make_float4(0.f,0.f,0.f,0.f); int i1 = 0;
  if (t < NTILE){
    int id0 = eidx[side * E_CNT + t * 16 + r];
    nfc = ((const float4*)nf)[id0 * 2 + half];
  }
  { int tn = t + nw;
    if (tn < NTILE) i1 = eidx[side * E_CNT + tn * 16 + r]; }

  for (; t < NTILE; t += nw){
    *(uint2*)&myctx[r * 40 + side * 8 + half * 4] =
        make_uint2(pk_bf16(nfc.x, nfc.y), pk_bf16(nfc.z, nfc.w));

    int tn1 = t + nw, tn2 = t + 2 * nw;
    float4 nfn = make_float4(0.f,0.f,0.f,0.f); int i2 = 0;
    if (tn1 < NTILE) nfn = ((const float4*)nf)[i1 * 2 + half];
    if (tn2 < NTILE) i2 = eidx[side * E_CNT + tn2 * 16 + r];

    asm volatile("s_waitcnt lgkmcnt(0)" ::: "memory");
    short8 bfr = *(const short8*)&myctx[m * 40 + q * 8];
    #pragma unroll
    for (int nt = 0; nt < 16; ++nt){
      f32x4 c = __builtin_amdgcn_mfma_f32_16x16x32_bf16(w1fr[nt], bfr, z4, 0, 0, 0);
      f32x4 hv = __builtin_elementwise_max(c, z4);
      sacc[nt] += hv;
      qacc[nt] += hv * hv;
    }
    nfc = nfn; i1 = i2;
  }

  #pragma unroll
  for (int nt = 0; nt < 16; ++nt){
    #pragma unroll
    for (int i = 0; i < 4; ++i){
      float v = sacc[nt][i], w = qacc[nt][i];
      v += __shfl_xor(v, 1); w += __shfl_xor(w, 1);
      v += __shfl_xor(v, 2); w += __shfl_xor(w, 2);
      v += __shfl_xor(v, 4); w += __shfl_xor(w, 4);
      v += __shfl_xor(v, 8); w += __shfl_xor(w, 8);
      if (m == 0){
        int j = nt * 16 + q * 4 + i;
        sred[0][wid][j] = v;
        sred[1][wid][j] = w;
      }
    }
  }
  __syncthreads();
  {
    int j = tid;
    float s0 = sred[0][0][j] + sred[0][1][j] + sred[0][2][j] + sred[0][3][j];
    float s1 = sred[1][0][j] + sred[1][1][j] + sred[1][2][j] + sred[1][3][j];
    part[blockIdx.x * 512 + j]       = s0;
    part[blockIdx.x * 512 + 256 + j] = s1;
  }
}

// ---------------- kRow: Y[r][0..7] = W[r][:] @ X[256][8] --------------------
// 256 blocks x 64 threads; lane-coalesced float4 row load; shuffle reduce.
__global__ __launch_bounds__(64) void kRow(const float* __restrict__ W,
                                           const float* __restrict__ X,
                                           float* __restrict__ Y)
{
  const int r = blockIdx.x, t = threadIdx.x;
  float4 w4 = ((const float4*)(W + r * HID))[t];   // j = 4t..4t+3
  float wv[4] = {w4.x, w4.y, w4.z, w4.w};
  float acc[8];
  #pragma unroll
  for (int d = 0; d < 8; ++d) acc[d] = 0.f;
  #pragma unroll
  for (int dj = 0; dj < 4; ++dj){
    int j = 4 * t + dj;
    float4 x0 = ((const float4*)(X + j * 8))[0];
    float4 x1 = ((const float4*)(X + j * 8))[1];
    acc[0] = fmaf(wv[dj], x0.x, acc[0]); acc[1] = fmaf(wv[dj], x0.y, acc[1]);
    acc[2] = fmaf(wv[dj], x0.z, acc[2]); acc[3] = fmaf(wv[dj], x0.w, acc[3]);
    acc[4] = fmaf(wv[dj], x1.x, acc[4]); acc[5] = fmaf(wv[dj], x1.y, acc[5]);
    acc[6] = fmaf(wv[dj], x1.z, acc[6]); acc[7] = fmaf(wv[dj], x1.w, acc[7]);
  }
  #pragma unroll
  for (int d = 0; d < 8; ++d){
    acc[d] += __shfl_xor(acc[d], 1);
    acc[d] += __shfl_xor(acc[d], 2);
    acc[d] += __shfl_xor(acc[d], 4);
    acc[d] += __shfl_xor(acc[d], 8);
    acc[d] += __shfl_xor(acc[d], 16);
    acc[d] += __shfl_xor(acc[d], 32);
  }
  if (t < 8) Y[r * 8 + t] = acc[t];
}

// ---------------- KC: stats-fold + Wd rows + bias ---------------------------
// 64 blocks x 256 threads; block b owns channels c = 4b..4b+3 and the static
// bias slice j = 4b..4b+3.
__global__ __launch_bounds__(256) void kC(
    const float* __restrict__ part, int nb,
    const float* __restrict__ gamma, const float* __restrict__ beta,
    const float* __restrict__ nW2,
    const float* __restrict__ T1s, const float* __restrict__ T2s,
    const float* __restrict__ Wp,
    const float* __restrict__ bv, const float* __restrict__ bo,
    const float* __restrict__ bp, const float* __restrict__ nb2,
    unsigned short* __restrict__ wd2t, float* __restrict__ bd2)
{
  __shared__ float T2L[2048];
  __shared__ float scr[2048];
  __shared__ float stL[8];
  const int t = threadIdx.x, b = blockIdx.x;

  for (int i = t; i < 2048; i += 256) T2L[i] = T2s[i];

  {
    int cl = t >> 6, i = t & 63;
    int c = b * 4 + cl;
    float s0 = 0.f, s1 = 0.f;
    for (int b2 = i; b2 < nb; b2 += 64){
      s0 += part[b2 * 512 + c];
      s1 += part[b2 * 512 + 256 + c];
    }
    scr[cl * 128 + i]      = s0;
    scr[cl * 128 + 64 + i] = s1;
  }
  __syncthreads();
  if (t < 4){
    float s0 = 0.f, s1 = 0.f;
    for (int i = 0; i < 64; ++i){
      s0 += scr[t * 128 + i];
      s1 += scr[t * 128 + 64 + i];
    }
    const float invE = 1.0f / (float)E_CNT;
    float mu  = s0 * invE;
    float var = fmaxf(s1 * invE - mu * mu, 0.f);
    float s   = gamma[b * 4 + t] * rsqrtf(var + 4.0f * 1e-5f);  // eps' = 4*eps
    stL[t]     = s;
    stL[4 + t] = beta[b * 4 + t] - mu * s;
  }
  __syncthreads();

  {
    int cl = t >> 6, d = (t >> 3) & 7, p8 = t & 7;
    int c = b * 4 + cl;
    const float* row = nW2 + c * HID;
    float a = 0.f;
    for (int j = p8 * 32; j < p8 * 32 + 32; ++j)
      a = fmaf(row[j], T2L[j * 8 + d], a);
    scr[t] = a;
  }
  __syncthreads();
  {
    int cl = t >> 6, d = (t >> 3) & 7, p8 = t & 7;
    if (p8 == 0){
      float w = 0.f;
      #pragma unroll
      for (int i = 0; i < 8; ++i) w += scr[t + i];
      int c = b * 4 + cl;
      wd2t[d * HID + c]       = f2bf(0.5f * stL[cl] * w);
      wd2t[(8 + d) * HID + c] = 0;                 // pad rows d=8..15
      scr[1024 + cl * 8 + d]  = stL[4 + cl] * w;   // tt*Wd contribution
    }
  }
  __syncthreads();
  if (t < 8){
    float a = scr[1024 + t] + scr[1024 + 8 + t] +
              scr[1024 + 16 + t] + scr[1024 + 24 + t];
    #pragma unroll
    for (int jj = 0; jj < 4; ++jj){     // static chain, j-slice of this block
      int j = 4 * b + jj;
      a = fmaf(nb2[j], T2L[j * 8 + t], a);
      a = fmaf(bv[j],  T1s[j * 8 + t], a);
      a = fmaf(bo[j],  Wp[j * 8 + t], a);
    }
    if (b == 0) a += bp[t];
    atomicAdd(&bd2[t], a);
  }
}

// ---------------- K3: out = edge_attr + h' @ Wd2 + bd2 ----------------------
__global__ __launch_bounds__(256, 3) void k3_main(
    const int* __restrict__ eidx, const float* __restrict__ nf,
    const float* __restrict__ ea,
    const float* __restrict__ W1, const float* __restrict__ b1,
    const unsigned short* __restrict__ wd2t, const float* __restrict__ bd2,
    float* __restrict__ out)
{
  __shared__ unsigned short w1l[256 * 24 + 32];
  __shared__ unsigned short ctx[4][16 * 40];
  __shared__ unsigned short hbuf[4][16 * 264];

  const int tid = threadIdx.x, lane = tid & 63, wid = tid >> 6;
  const int gw = blockIdx.x * 4 + wid, ngw = gridDim.x * 4;
  const int m = lane & 15, q = lane >> 4;
  const int r = lane >> 2, side = (lane >> 1) & 1, half = lane & 1;

  init_w1_lds(w1l, W1, b1, tid);

  short8 w2fr[8];
  #pragma unroll
  for (int kb = 0; kb < 8; ++kb)
    w2fr[kb] = *(const short8*)&wd2t[m * HID + kb * 32 + q * 8];
  const float bd2v = (m < 8) ? 0.5f * bd2[m] : 0.f;

  unsigned short* myctx = ctx[wid];
  unsigned short* myh   = hbuf[wid];
  for (int i = lane; i < 16 * 40; i += 64) myctx[i] = 0;
  if (lane < 16) myctx[lane * 40 + 16] = 0x3F80;
  __syncthreads();

  short8 w1fr[16];                 // hoisted
  #pragma unroll
  for (int nt = 0; nt < 16; ++nt)
    w1fr[nt] = *(const short8*)&w1l[(nt * 16 + m) * 24 + q * 8];

  const f32x4 z4 = {0.f, 0.f, 0.f, 0.f};

  int t = gw;
  float4 nfc = make_float4(0.f,0.f,0.f,0.f); int i1 = 0;
  if (t < NTILE){
    int id0 = eidx[side * E_CNT + t * 16 + r];
    nfc = ((const float4*)nf)[id0 * 2 + half];
  }
  { int tn = t + ngw;
    if (tn < NTILE) i1 = eidx[side * E_CNT + tn * 16 + r]; }

  const bool dok = (m < 8);
  for (; t < NTILE; t += ngw){
    *(uint2*)&myctx[r * 40 + side * 8 + half * 4] =
        make_uint2(pk_bf16(nfc.x, nfc.y), pk_bf16(nfc.z, nfc.w));

    float eav[4];
    #pragma unroll
    for (int i = 0; i < 4; ++i)
      eav[i] = dok ? ea[(t * 16 + q * 4 + i) * 8 + m] : 0.f;

    int tn1 = t + ngw, tn2 = t + 2 * ngw;
    float4 nfn = make_float4(0.f,0.f,0.f,0.f); int i2 = 0;
    if (tn1 < NTILE) nfn = ((const float4*)nf)[i1 * 2 + half];
    if (tn2 < NTILE) i2 = eidx[side * E_CNT + tn2 * 16 + r];

    asm volatile("s_waitcnt lgkmcnt(0)" ::: "memory");
    short8 bfr = *(const short8*)&myctx[m * 40 + q * 8];
    // mm1: h' tile -> packed bf16 -> LDS (j-contiguous per lane)
    #pragma unroll
    for (int nt = 0; nt < 16; ++nt){
      f32x4 c = __builtin_amdgcn_mfma_f32_16x16x32_bf16(w1fr[nt], bfr, z4, 0, 0, 0);
      f32x4 hv = __builtin_elementwise_max(c, z4);
      *(uint2*)&myh[m * 264 + nt * 16 + q * 4] =
          make_uint2(pk_bf16(hv[0], hv[1]), pk_bf16(hv[2], hv[3]));
    }
    asm volatile("s_waitcnt lgkmcnt(0)" ::: "memory");
    // mm2: out tile = h' @ Wd2
    f32x4 acc = z4;
    #pragma unroll
    for (int kb = 0; kb < 8; ++kb){
      short8 afr = *(const short8*)&myh[m * 264 + kb * 32 + q * 8];
      acc = __builtin_amdgcn_mfma_f32_16x16x32_bf16(afr, w2fr[kb], acc, 0, 0, 0);
    }
    if (dok){
      #pragma unroll
      for (int i = 0; i < 4; ++i){
        float o = eav[i] + acc[i] + bd2v;
        out[(t * 16 + q * 4 + i) * 8 + m] = o;
      }
    }
    nfc = nfn; i1 = i2;
  }
}

extern "C" void kernel_launch(void* const* d_in, const int* in_sizes, int n_in,
                              void* d_out, int out_size, void* d_ws, size_t ws_size,
                              hipStream_t stream)
{
  const float* ea   = (const float*)d_in[0];
  const float* nf   = (const float*)d_in[1];
  const int*   eidx = (const int*)d_in[2];
  // d_in[3..8] = edge-encoder params: dead code in the reference.
  const float* nW1    = (const float*)d_in[9];
  const float* nb1    = (const float*)d_in[10];
  const float* ngamma = (const float*)d_in[11];
  const float* nbeta  = (const float*)d_in[12];
  const float* nW2    = (const float*)d_in[13];
  const float* nb2    = (const float*)d_in[14];
  const float* Wv     = (const float*)d_in[15];
  const float* bv     = (const float*)d_in[16];
  const float* Wo     = (const float*)d_in[17];
  const float* bo     = (const float*)d_in[18];
  const float* Wp     = (const float*)d_in[19];
  const float* bp     = (const float*)d_in[20];

  // ws layout: [nb*512 f32 part][wd2t 16x256 bf16][bd2 16 f32][T1][T2]
  long avail = (long)ws_size - 8192 - 64 - 16384;
  int nb = (int)(avail / 2048);
  if (nb > 768) nb = 768;
  if (nb < 1)   nb = 1;

  char* ws = (char*)d_ws;
  size_t off = (size_t)nb * 2048;
  float* ws_part          = (float*)(ws + 0);
  unsigned short* ws_wd2t = (unsigned short*)(ws + off);
  float* ws_bd2           = (float*)(ws + off + 8192);
  float* ws_t1            = (float*)(ws + off + 8192 + 64);
  float* ws_t2            = (float*)(ws + off + 8192 + 64 + 8192);

  k1_stats<<<dim3(nb), dim3(256), 0, stream>>>(eidx, nf, nW1, nb1,
                                               ws_part, ws_bd2);
  kRow<<<dim3(256), dim3(64), 0, stream>>>(Wo, Wp, ws_t1);      // T1 = Wo@Wp
  kRow<<<dim3(256), dim3(64), 0, stream>>>(Wv, ws_t1, ws_t2);   // T2 = Wv@T1
  kC<<<dim3(64), dim3(256), 0, stream>>>(
      ws_part, nb, ngamma, nbeta, nW2, ws_t1, ws_t2, Wp, bv, bo, bp, nb2,
      ws_wd2t, ws_bd2);
  k3_main<<<dim3(768), dim3(256), 0, stream>>>(
      eidx, nf, ea, nW1, nb1, ws_wd2t, ws_bd2, (float*)d_out);
}

// Round 8
// 184.723 us; speedup vs baseline: 1.3524x; 1.3524x over previous
//
#include <hip/hip_runtime.h>
#include <hip/hip_bf16.h>
#include <string.h>

#define E_CNT 500000
#define N_CNT 100000
#define HID   256
#define NTILE 31250   // E/16

typedef short short8 __attribute__((ext_vector_type(8)));
typedef float f32x4 __attribute__((ext_vector_type(4)));

__device__ __forceinline__ unsigned short f2bf(float f){
  union { float f; unsigned int i; } v; v.f = f;
  unsigned int u = v.i;
  u = u + 0x7FFFu + ((u >> 16) & 1u);
  return (unsigned short)(u >> 16);
}

__device__ __forceinline__ unsigned int pk_bf16(float a, float b){
  __hip_bfloat162 p = __float22bfloat162_rn(make_float2(a, b));
  unsigned int u; memcpy(&u, &p, 4); return u;
}

// W1-augmented A-fragment staging. Row ch (24 shorts, 48 B):
// k0..7=W1[k][ch], k8..15=W1 again, k16=2*b1[ch], k17..23=0.
__device__ __forceinline__ void init_w1_lds(unsigned short* w1l,
                                            const float* W1, const float* b1,
                                            int tid){
  int ch = tid;
  #pragma unroll
  for (int j = 0; j < 8; ++j){
    unsigned short w = f2bf(W1[j * HID + ch]);
    w1l[ch * 24 + j]     = w;
    w1l[ch * 24 + 8 + j] = w;
  }
  w1l[ch * 24 + 16] = f2bf(2.0f * b1[ch]);
  #pragma unroll
  for (int j = 17; j < 24; ++j) w1l[ch * 24 + j] = 0;
  if (tid < 32) w1l[256 * 24 + tid] = 0;   // tail pad for q=3 of ch=255
}

// ---------------- K1: batch stats of h' = relu((nf[s]+nf[t])@W1 + 2 b1) ------
// Channel-split wave pairs: wave wid covers channels (wid&1)*128..+127 for
// edge-tile stream pair = gw>>1 (waves of a pair gather redundantly -> no
// in-loop barrier). Keeps hoisted fragments AND fits the register budget:
// w1fr 32 + sacc/qacc 64 + misc ~30 < 168 regs @ 3 waves/SIMD -> no spill.
__global__ __launch_bounds__(256, 3) void k1_stats(
    const int* __restrict__ eidx, const float* __restrict__ nf,
    const float* __restrict__ W1, const float* __restrict__ b1,
    float* __restrict__ part, float* __restrict__ bd2)
{
  __shared__ unsigned short w1l[256 * 24 + 32];
  __shared__ unsigned short ctx[4][16 * 40];
  __shared__ float sred[2][4][128];

  const int tid = threadIdx.x, lane = tid & 63, wid = tid >> 6;
  const int cg = wid & 1;                         // channel group
  const int pair = (blockIdx.x * 4 + wid) >> 1;   // edge-tile stream
  const int npair = gridDim.x * 2;
  const int m = lane & 15, q = lane >> 4;
  const int r = lane >> 2, side = (lane >> 1) & 1, half = lane & 1;

  if (blockIdx.x == 0 && tid < 16) bd2[tid] = 0.f;   // kC atomicAdds later

  init_w1_lds(w1l, W1, b1, tid);

  unsigned short* myctx = ctx[wid];
  for (int i = lane; i < 16 * 40; i += 64) myctx[i] = 0;
  if (lane < 16) myctx[lane * 40 + 16] = 0x3F80;   // bf16 1.0 at k=16
  __syncthreads();

  short8 w1fr[8];                  // hoisted once; 32 VGPRs
  #pragma unroll
  for (int nt = 0; nt < 8; ++nt)
    w1fr[nt] = *(const short8*)&w1l[((cg * 8 + nt) * 16 + m) * 24 + q * 8];

  const f32x4 z4 = {0.f, 0.f, 0.f, 0.f};
  f32x4 sacc[8], qacc[8];
  #pragma unroll
  for (int nt = 0; nt < 8; ++nt){ sacc[nt] = z4; qacc[nt] = z4; }

  int t = pair;
  float4 nfc = make_float4(0.f,0.f,0.f,0.f); int i1 = 0;
  if (t < NTILE){
    int id0 = eidx[side * E_CNT + t * 16 + r];
    nfc = ((const float4*)nf)[id0 * 2 + half];
  }
  { int tn = t + npair;
    if (tn < NTILE) i1 = eidx[side * E_CNT + tn * 16 + r]; }

  for (; t < NTILE; t += npair){
    *(uint2*)&myctx[r * 40 + side * 8 + half * 4] =
        make_uint2(pk_bf16(nfc.x, nfc.y), pk_bf16(nfc.z, nfc.w));

    int tn1 = t + npair, tn2 = t + 2 * npair;
    float4 nfn = make_float4(0.f,0.f,0.f,0.f); int i2 = 0;
    if (tn1 < NTILE) nfn = ((const float4*)nf)[i1 * 2 + half];
    if (tn2 < NTILE) i2 = eidx[side * E_CNT + tn2 * 16 + r];

    asm volatile("s_waitcnt lgkmcnt(0)" ::: "memory");
    short8 bfr = *(const short8*)&myctx[m * 40 + q * 8];
    #pragma unroll
    for (int nt = 0; nt < 8; ++nt){
      f32x4 c = __builtin_amdgcn_mfma_f32_16x16x32_bf16(w1fr[nt], bfr, z4, 0, 0, 0);
      f32x4 hv = __builtin_elementwise_max(c, z4);
      sacc[nt] += hv;
      qacc[nt] += hv * hv;
    }
    nfc = nfn; i1 = i2;
  }

  #pragma unroll
  for (int nt = 0; nt < 8; ++nt){
    #pragma unroll
    for (int i = 0; i < 4; ++i){
      float v = sacc[nt][i], w = qacc[nt][i];
      v += __shfl_xor(v, 1); w += __shfl_xor(w, 1);
      v += __shfl_xor(v, 2); w += __shfl_xor(w, 2);
      v += __shfl_xor(v, 4); w += __shfl_xor(w, 4);
      v += __shfl_xor(v, 8); w += __shfl_xor(w, 8);
      if (m == 0){
        int loc = nt * 16 + q * 4 + i;   // 0..127 within channel group
        sred[0][wid][loc] = v;
        sred[1][wid][loc] = w;
      }
    }
  }
  __syncthreads();
  {
    int j = tid, hf = j >> 7, loc = j & 127;
    float s0 = sred[0][hf][loc] + sred[0][hf + 2][loc];
    float s1 = sred[1][hf][loc] + sred[1][hf + 2][loc];
    part[blockIdx.x * 512 + j]       = s0;
    part[blockIdx.x * 512 + 256 + j] = s1;
  }
}

// ---------------- kRow: Y[r][0..7] = W[r][:] @ X[256][8] --------------------
__global__ __launch_bounds__(64) void kRow(const float* __restrict__ W,
                                           const float* __restrict__ X,
                                           float* __restrict__ Y)
{
  const int r = blockIdx.x, t = threadIdx.x;
  float4 w4 = ((const float4*)(W + r * HID))[t];   // j = 4t..4t+3
  float wv[4] = {w4.x, w4.y, w4.z, w4.w};
  float acc[8];
  #pragma unroll
  for (int d = 0; d < 8; ++d) acc[d] = 0.f;
  #pragma unroll
  for (int dj = 0; dj < 4; ++dj){
    int j = 4 * t + dj;
    float4 x0 = ((const float4*)(X + j * 8))[0];
    float4 x1 = ((const float4*)(X + j * 8))[1];
    acc[0] = fmaf(wv[dj], x0.x, acc[0]); acc[1] = fmaf(wv[dj], x0.y, acc[1]);
    acc[2] = fmaf(wv[dj], x0.z, acc[2]); acc[3] = fmaf(wv[dj], x0.w, acc[3]);
    acc[4] = fmaf(wv[dj], x1.x, acc[4]); acc[5] = fmaf(wv[dj], x1.y, acc[5]);
    acc[6] = fmaf(wv[dj], x1.z, acc[6]); acc[7] = fmaf(wv[dj], x1.w, acc[7]);
  }
  #pragma unroll
  for (int d = 0; d < 8; ++d){
    acc[d] += __shfl_xor(acc[d], 1);
    acc[d] += __shfl_xor(acc[d], 2);
    acc[d] += __shfl_xor(acc[d], 4);
    acc[d] += __shfl_xor(acc[d], 8);
    acc[d] += __shfl_xor(acc[d], 16);
    acc[d] += __shfl_xor(acc[d], 32);
  }
  if (t < 8) Y[r * 8 + t] = acc[t];
}

// ---------------- KC: stats-fold + Wd rows + bias ---------------------------
__global__ __launch_bounds__(256) void kC(
    const float* __restrict__ part, int nb,
    const float* __restrict__ gamma, const float* __restrict__ beta,
    const float* __restrict__ nW2,
    const float* __restrict__ T1s, const float* __restrict__ T2s,
    const float* __restrict__ Wp,
    const float* __restrict__ bv, const float* __restrict__ bo,
    const float* __restrict__ bp, const float* __restrict__ nb2,
    unsigned short* __restrict__ wd2t, float* __restrict__ bd2)
{
  __shared__ float T2L[2048];
  __shared__ float scr[2048];
  __shared__ float stL[8];
  const int t = threadIdx.x, b = blockIdx.x;

  for (int i = t; i < 2048; i += 256) T2L[i] = T2s[i];

  {
    int cl = t >> 6, i = t & 63;
    int c = b * 4 + cl;
    float s0 = 0.f, s1 = 0.f;
    for (int b2 = i; b2 < nb; b2 += 64){
      s0 += part[b2 * 512 + c];
      s1 += part[b2 * 512 + 256 + c];
    }
    scr[cl * 128 + i]      = s0;
    scr[cl * 128 + 64 + i] = s1;
  }
  __syncthreads();
  if (t < 4){
    float s0 = 0.f, s1 = 0.f;
    for (int i = 0; i < 64; ++i){
      s0 += scr[t * 128 + i];
      s1 += scr[t * 128 + 64 + i];
    }
    const float invE = 1.0f / (float)E_CNT;
    float mu  = s0 * invE;
    float var = fmaxf(s1 * invE - mu * mu, 0.f);
    float s   = gamma[b * 4 + t] * rsqrtf(var + 4.0f * 1e-5f);  // eps' = 4*eps
    stL[t]     = s;
    stL[4 + t] = beta[b * 4 + t] - mu * s;
  }
  __syncthreads();

  {
    int cl = t >> 6, d = (t >> 3) & 7, p8 = t & 7;
    int c = b * 4 + cl;
    const float* row = nW2 + c * HID;
    float a = 0.f;
    for (int j = p8 * 32; j < p8 * 32 + 32; ++j)
      a = fmaf(row[j], T2L[j * 8 + d], a);
    scr[t] = a;
  }
  __syncthreads();
  {
    int cl = t >> 6, d = (t >> 3) & 7, p8 = t & 7;
    if (p8 == 0){
      float w = 0.f;
      #pragma unroll
      for (int i = 0; i < 8; ++i) w += scr[t + i];
      int c = b * 4 + cl;
      wd2t[d * HID + c]       = f2bf(0.5f * stL[cl] * w);
      wd2t[(8 + d) * HID + c] = 0;                 // pad rows d=8..15
      scr[1024 + cl * 8 + d]  = stL[4 + cl] * w;   // tt*Wd contribution
    }
  }
  __syncthreads();
  if (t < 8){
    float a = scr[1024 + t] + scr[1024 + 8 + t] +
              scr[1024 + 16 + t] + scr[1024 + 24 + t];
    #pragma unroll
    for (int jj = 0; jj < 4; ++jj){     // static chain, j-slice of this block
      int j = 4 * b + jj;
      a = fmaf(nb2[j], T2L[j * 8 + t], a);
      a = fmaf(bv[j],  T1s[j * 8 + t], a);
      a = fmaf(bo[j],  Wp[j * 8 + t], a);
    }
    if (b == 0) a += bp[t];
    atomicAdd(&bd2[t], a);
  }
}

// ---------------- K3: out = edge_attr + h' @ Wd2 + bd2 ----------------------
__global__ __launch_bounds__(256, 3) void k3_main(
    const int* __restrict__ eidx, const float* __restrict__ nf,
    const float* __restrict__ ea,
    const float* __restrict__ W1, const float* __restrict__ b1,
    const unsigned short* __restrict__ wd2t, const float* __restrict__ bd2,
    float* __restrict__ out)
{
  __shared__ unsigned short w1l[256 * 24 + 32];
  __shared__ unsigned short ctx[4][16 * 40];
  __shared__ unsigned short hbuf[4][16 * 264];

  const int tid = threadIdx.x, lane = tid & 63, wid = tid >> 6;
  const int gw = blockIdx.x * 4 + wid, ngw = gridDim.x * 4;
  const int m = lane & 15, q = lane >> 4;
  const int r = lane >> 2, side = (lane >> 1) & 1, half = lane & 1;

  init_w1_lds(w1l, W1, b1, tid);

  short8 w2fr[8];
  #pragma unroll
  for (int kb = 0; kb < 8; ++kb)
    w2fr[kb] = *(const short8*)&wd2t[m * HID + kb * 32 + q * 8];
  const float bd2v = (m < 8) ? 0.5f * bd2[m] : 0.f;

  unsigned short* myctx = ctx[wid];
  unsigned short* myh   = hbuf[wid];
  for (int i = lane; i < 16 * 40; i += 64) myctx[i] = 0;
  if (lane < 16) myctx[lane * 40 + 16] = 0x3F80;
  __syncthreads();

  short8 w1fr[16];                 // hoisted
  #pragma unroll
  for (int nt = 0; nt < 16; ++nt)
    w1fr[nt] = *(const short8*)&w1l[(nt * 16 + m) * 24 + q * 8];

  const f32x4 z4 = {0.f, 0.f, 0.f, 0.f};

  int t = gw;
  float4 nfc = make_float4(0.f,0.f,0.f,0.f); int i1 = 0;
  if (t < NTILE){
    int id0 = eidx[side * E_CNT + t * 16 + r];
    nfc = ((const float4*)nf)[id0 * 2 + half];
  }
  { int tn = t + ngw;
    if (tn < NTILE) i1 = eidx[side * E_CNT + tn * 16 + r]; }

  const bool dok = (m < 8);
  for (; t < NTILE; t += ngw){
    *(uint2*)&myctx[r * 40 + side * 8 + half * 4] =
        make_uint2(pk_bf16(nfc.x, nfc.y), pk_bf16(nfc.z, nfc.w));

    float eav[4];
    #pragma unroll
    for (int i = 0; i < 4; ++i)
      eav[i] = dok ? ea[(t * 16 + q * 4 + i) * 8 + m] : 0.f;

    int tn1 = t + ngw, tn2 = t + 2 * ngw;
    float4 nfn = make_float4(0.f,0.f,0.f,0.f); int i2 = 0;
    if (tn1 < NTILE) nfn = ((const float4*)nf)[i1 * 2 + half];
    if (tn2 < NTILE) i2 = eidx[side * E_CNT + tn2 * 16 + r];

    asm volatile("s_waitcnt lgkmcnt(0)" ::: "memory");
    short8 bfr = *(const short8*)&myctx[m * 40 + q * 8];
    // mm1: h' tile -> packed bf16 -> LDS (j-contiguous per lane)
    #pragma unroll
    for (int nt = 0; nt < 16; ++nt){
      f32x4 c = __builtin_amdgcn_mfma_f32_16x16x32_bf16(w1fr[nt], bfr, z4, 0, 0, 0);
      f32x4 hv = __builtin_elementwise_max(c, z4);
      *(uint2*)&myh[m * 264 + nt * 16 + q * 4] =
          make_uint2(pk_bf16(hv[0], hv[1]), pk_bf16(hv[2], hv[3]));
    }
    asm volatile("s_waitcnt lgkmcnt(0)" ::: "memory");
    // mm2: out tile = h' @ Wd2
    f32x4 acc = z4;
    #pragma unroll
    for (int kb = 0; kb < 8; ++kb){
      short8 afr = *(const short8*)&myh[m * 264 + kb * 32 + q * 8];
      acc = __builtin_amdgcn_mfma_f32_16x16x32_bf16(afr, w2fr[kb], acc, 0, 0, 0);
    }
    if (dok){
      #pragma unroll
      for (int i = 0; i < 4; ++i){
        float o = eav[i] + acc[i] + bd2v;
        out[(t * 16 + q * 4 + i) * 8 + m] = o;
      }
    }
    nfc = nfn; i1 = i2;
  }
}

extern "C" void kernel_launch(void* const* d_in, const int* in_sizes, int n_in,
                              void* d_out, int out_size, void* d_ws, size_t ws_size,
                              hipStream_t stream)
{
  const float* ea   = (const float*)d_in[0];
  const float* nf   = (const float*)d_in[1];
  const int*   eidx = (const int*)d_in[2];
  // d_in[3..8] = edge-encoder params: dead code in the reference.
  const float* nW1    = (const float*)d_in[9];
  const float* nb1    = (const float*)d_in[10];
  const float* ngamma = (const float*)d_in[11];
  const float* nbeta  = (const float*)d_in[12];
  const float* nW2    = (const float*)d_in[13];
  const float* nb2    = (const float*)d_in[14];
  const float* Wv     = (const float*)d_in[15];
  const float* bv     = (const float*)d_in[16];
  const float* Wo     = (const float*)d_in[17];
  const float* bo     = (const float*)d_in[18];
  const float* Wp     = (const float*)d_in[19];
  const float* bp     = (const float*)d_in[20];

  // ws layout: [nb*512 f32 part][wd2t 16x256 bf16][bd2 16 f32][T1][T2]
  long avail = (long)ws_size - 8192 - 64 - 16384;
  int nb = (int)(avail / 2048);
  if (nb > 768) nb = 768;
  if (nb < 1)   nb = 1;

  char* ws = (char*)d_ws;
  size_t off = (size_t)nb * 2048;
  float* ws_part          = (float*)(ws + 0);
  unsigned short* ws_wd2t = (unsigned short*)(ws + off);
  float* ws_bd2           = (float*)(ws + off + 8192);
  float* ws_t1            = (float*)(ws + off + 8192 + 64);
  float* ws_t2            = (float*)(ws + off + 8192 + 64 + 8192);

  k1_stats<<<dim3(nb), dim3(256), 0, stream>>>(eidx, nf, nW1, nb1,
                                               ws_part, ws_bd2);
  kRow<<<dim3(256), dim3(64), 0, stream>>>(Wo, Wp, ws_t1);      // T1 = Wo@Wp
  kRow<<<dim3(256), dim3(64), 0, stream>>>(Wv, ws_t1, ws_t2);   // T2 = Wv@T1
  kC<<<dim3(64), dim3(256), 0, stream>>>(
      ws_part, nb, ngamma, nbeta, nW2, ws_t1, ws_t2, Wp, bv, bo, bp, nb2,
      ws_wd2t, ws_bd2);
  k3_main<<<dim3(768), dim3(256), 0, stream>>>(
      eidx, nf, ea, nW1, nb1, ws_wd2t, ws_bd2, (float*)d_out);
}